// Round 7
// baseline (197.911 us; speedup 1.0000x reference)
//
#include <hip/hip_runtime.h>
#include <hip/hip_bf16.h>

// MMD loss: source/target 4096x256 fp32, output = scalar fp32. N=8192, D=256.
//
// Two kernels total (last-block tickets fuse the scalar stages):
//  k_prep : fp32 -> bf16 in MFMA-native tiled layout G2 + row sq[] (from the
//           SAME bf16 values -> diagonal exact) + colsum/sqsum atomics;
//           LAST block computes neg_gamma2 = -log2(e)/(16*bw).
//  k_mmd  : one wave per 64x64 pair-tile (upper triangle), fragments loaded
//           straight from L2 (G2 frag = contiguous 1KB block), HALF-K (128)
//           register-resident per step -> one vmcnt wait per half, 64-MFMA
//           burst under s_setprio. No LDS, no barriers in the hot path.
//           LAST block reduces the 256 slot accumulators and writes out.
//
// G2 layout: tile t (64 rows), frag(kc,fr) contiguous 1KB:
//   G2[t*16384 + (kc*4+fr)*512 + lane*8 + e]
//   row = t*64 + fr*16 + (lane&15); k = kc*32 + (lane>>4)*8 + e
// (A- and B-fragment layouts coincide for the Gram product.)
//
// ws doubles: d[0..255]=colsum, d[256]=neg_gamma2, d[257]=sqsum,
//             d[258..513]=slots; ints at byte 4112: tick_prep, tick_mmd;
//             float sq[8192] at 4608; bf16 G2[8192*256] at 40960.
#define WS_D_COLSUM 0
#define WS_D_NEGG   256
#define WS_D_SQSUM  257
#define WS_D_SLOT   258
#define WS_SLOTS    256
#define WS_TICK_OFF 4112
#define WS_SQ_OFF   4608
#define WS_G_OFF    40960

#define NROW 8192
#define HALF 4096
#define DIM  256
#define TT   64
#define NT   128                   // row-tiles
#define NPAIR (NT * (NT + 1) / 2)  // 8256
#define NBLK  (NPAIR / 4)          // 2064 blocks x 4 waves
#define TILE_US 16384              // ushorts per tile (32 KB)

typedef short  short8 __attribute__((ext_vector_type(8)));
typedef float  f32x4  __attribute__((ext_vector_type(4)));
typedef unsigned short us4 __attribute__((ext_vector_type(4)));

static __device__ __forceinline__ unsigned short f2bfbits(float f) {
    __hip_bfloat16 h = __float2bfloat16(f);   // RNE
    return *reinterpret_cast<unsigned short*>(&h);
}
static __device__ __forceinline__ float bfbits2f(unsigned short u) {
    return __uint_as_float(((unsigned int)u) << 16);
}

// ---------- kernel A: cvt->G2 + row-sq + colsum/sqsum + bandwidth ----------
// 256 blocks x 256 threads; block handles 32 rows; wave w rows r0+w+4i, i<8.
__global__ __launch_bounds__(256) void k_prep(const float* __restrict__ src,
                                              const float* __restrict__ tgt,
                                              unsigned short* __restrict__ G2,
                                              float* __restrict__ sq,
                                              double* __restrict__ wsd,
                                              int* __restrict__ tick) {
    __shared__ float cs_lds[4 * 256];
    __shared__ double sq_lds[4];
    __shared__ double red2[256];
    __shared__ int is_last;

    int t = threadIdx.x, wid = t >> 6, lane = t & 63;
    int r0 = blockIdx.x * 32;
    int c4 = lane * 4;
    // G2 lane-invariant part: kc=lane>>3, kl=(lane>>1)&3, e4=(lane&1)*4
    int lanepart = (lane >> 3) * 2048 + ((lane >> 1) & 3) * 128 + (lane & 1) * 4;

    float cs0 = 0.f, cs1 = 0.f, cs2 = 0.f, cs3 = 0.f;
    double wsq = 0.0;
    for (int i = 0; i < 8; ++i) {
        int row = r0 + wid + i * 4;
        const float* base = (row < HALF) ? (src + (size_t)row * DIM)
                                         : (tgt + (size_t)(row - HALF) * DIM);
        float4 v = *(const float4*)(base + c4);
        unsigned short u0 = f2bfbits(v.x), u1 = f2bfbits(v.y),
                       u2 = f2bfbits(v.z), u3 = f2bfbits(v.w);
        us4 uu = {u0, u1, u2, u3};
        size_t tb = (size_t)(row >> 6) * TILE_US + (((row >> 4) & 3) * 512) + ((row & 15) * 8);
        *(us4*)(G2 + tb + lanepart) = uu;
        float r0f = bfbits2f(u0), r1f = bfbits2f(u1),
              r2f = bfbits2f(u2), r3f = bfbits2f(u3);
        cs0 += r0f; cs1 += r1f; cs2 += r2f; cs3 += r3f;
        float s = r0f * r0f + r1f * r1f + r2f * r2f + r3f * r3f;
        #pragma unroll
        for (int off = 32; off; off >>= 1) s += __shfl_down(s, off);
        if (lane == 0) { sq[row] = s; wsq += (double)s; }
    }
    cs_lds[wid * 256 + c4 + 0] = cs0;
    cs_lds[wid * 256 + c4 + 1] = cs1;
    cs_lds[wid * 256 + c4 + 2] = cs2;
    cs_lds[wid * 256 + c4 + 3] = cs3;
    if (lane == 0) sq_lds[wid] = wsq;
    __syncthreads();
    double s = (double)cs_lds[t] + (double)cs_lds[256 + t] +
               (double)cs_lds[512 + t] + (double)cs_lds[768 + t];
    atomicAdd(&wsd[WS_D_COLSUM + t], s);
    if (t == 0)
        atomicAdd(&wsd[WS_D_SQSUM], sq_lds[0] + sq_lds[1] + sq_lds[2] + sq_lds[3]);

    // ---- last block computes bandwidth ----
    __threadfence();
    if (t == 0) is_last = (atomicAdd(tick, 1) == (int)gridDim.x - 1);
    __syncthreads();
    if (!is_last) return;
    double c = atomicAdd(&wsd[WS_D_COLSUM + t], 0.0);  // coherent read-back
    red2[t] = c * c;
    __syncthreads();
    for (int off = 128; off; off >>= 1) {
        if (t < off) red2[t] += red2[t + off];
        __syncthreads();
    }
    if (t == 0) {
        double S = atomicAdd(&wsd[WS_D_SQSUM], 0.0);
        const double N = (double)NROW;
        double sum_l2 = 2.0 * N * S - 2.0 * red2[0];
        double bw = sum_l2 / (N * N - N);
        bw = bw / 4.0;  // KERNEL_MUL ** (KERNEL_NUM//2) = 2^2
        wsd[WS_D_NEGG] = -1.4426950408889634 / (16.0 * bw);  // exp2 scaling
    }
}

// ---------- kernel D: one wave per 64x64 pair-tile, register-resident K ----
__global__ __launch_bounds__(256, 2) void k_mmd(const unsigned short* __restrict__ G2,
                                                const float* __restrict__ sq,
                                                const double* __restrict__ wsd,
                                                double* __restrict__ slots,
                                                float* __restrict__ out,
                                                int* __restrict__ tick) {
    __shared__ int is_last;
    __shared__ double fin[4];

    // XCD-chunked bijective swizzle (NBLK = 2064 = 8*258)
    int bid = blockIdx.x;
    int swz = (bid & 7) * (NBLK / 8) + (bid >> 3);

    int t = threadIdx.x, wid = t >> 6, lane = t & 63;
    int p = swz * 4 + wid;   // pair index 0..8255 (wave-uniform)

    // closed-form triangular decode: start(ti) = 128*ti - ti*(ti-1)/2
    int ti = (int)((257.0f - sqrtf(66049.0f - 8.0f * (float)p)) * 0.5f);
    ti = ti < 0 ? 0 : (ti > 127 ? 127 : ti);
    while (ti > 0 && p < 128 * ti - ((ti * (ti - 1)) >> 1)) --ti;
    while (p >= 128 * (ti + 1) - (((ti + 1) * ti) >> 1)) ++ti;
    int tj = ti + (p - (128 * ti - ((ti * (ti - 1)) >> 1)));

    const unsigned short* Ab = G2 + (size_t)ti * TILE_US;
    const unsigned short* Bb = G2 + (size_t)tj * TILE_US;
    int lo = lane * 8;

    const f32x4 zero4 = {0.f, 0.f, 0.f, 0.f};
    f32x4 acc[4][4];
    #pragma unroll
    for (int i = 0; i < 4; ++i)
        #pragma unroll
        for (int j = 0; j < 4; ++j) acc[i][j] = zero4;

    #pragma unroll
    for (int h = 0; h < 2; ++h) {
        short8 a[4][4], b[4][4];   // [kf][fr] — all compile-time indexed
        #pragma unroll
        for (int kf = 0; kf < 4; ++kf)
            #pragma unroll
            for (int fr = 0; fr < 4; ++fr) {
                int fo = (((h * 4 + kf) * 4 + fr) * 512) + lo;
                a[kf][fr] = *(const short8*)&Ab[fo];
                b[kf][fr] = *(const short8*)&Bb[fo];
            }
        __builtin_amdgcn_s_setprio(1);
        #pragma unroll
        for (int kf = 0; kf < 4; ++kf)
            #pragma unroll
            for (int i = 0; i < 4; ++i)
                #pragma unroll
                for (int j = 0; j < 4; ++j)
                    acc[i][j] = __builtin_amdgcn_mfma_f32_16x16x32_bf16(
                        a[kf][i], b[kf][j], acc[i][j], 0, 0, 0);
        __builtin_amdgcn_s_setprio(0);
    }

    // epilogue: x = l2*ng2 = min(sqa' + sqb' + acc*m2g, 0);  kernels = sum e^(2^i)
    // C/D layout (m89): col = lane&15, row = (lane>>4)*4 + reg
    int gi0 = ti * TT, gj0 = tj * TT;
    float ng2 = (float)wsd[WS_D_NEGG];       // negative
    float m2g = -2.0f * ng2;                 // positive
    int rl16 = lane & 15, rgrp = lane >> 4;

    float sqb4[4];
    #pragma unroll
    for (int j = 0; j < 4; ++j) sqb4[j] = sq[gj0 + j * 16 + rl16] * ng2;

    float tsum = 0.f;
    #pragma unroll
    for (int i = 0; i < 4; ++i) {
        float sqa4[4];
        #pragma unroll
        for (int rr = 0; rr < 4; ++rr)
            sqa4[rr] = sq[gi0 + i * 16 + rgrp * 4 + rr] * ng2;
        #pragma unroll
        for (int j = 0; j < 4; ++j) {
            #pragma unroll
            for (int rr = 0; rr < 4; ++rr) {
                float x = fminf(fmaf(acc[i][j][rr], m2g, sqa4[rr] + sqb4[j]), 0.f);
                float e   = exp2f(x);
                float e2  = e * e;
                float e4  = e2 * e2;
                float e8  = e4 * e4;
                float e16 = e8 * e8;
                tsum += (e + e2) + (e4 + e8) + e16;
            }
        }
    }

    float w = ((ti < NT / 2) == (tj < NT / 2)) ? 1.f : -1.f;
    if (ti != tj) w *= 2.f;   // off-diagonal tiles count twice (symmetry)
    double dsum = (double)tsum * (double)w;

    #pragma unroll
    for (int off = 32; off; off >>= 1) dsum += __shfl_down(dsum, off);
    if (lane == 0) atomicAdd(&slots[p & (WS_SLOTS - 1)], dsum);

    // ---- last block finalizes ----
    __syncthreads();
    __threadfence();
    if (t == 0) is_last = (atomicAdd(tick, 1) == (int)gridDim.x - 1);
    __syncthreads();
    if (!is_last) return;
    double v = atomicAdd(&slots[t], 0.0);  // coherent read-back
    #pragma unroll
    for (int off = 32; off; off >>= 1) v += __shfl_down(v, off);
    if (lane == 0) fin[wid] = v;
    __syncthreads();
    if (t == 0)
        out[0] = (float)((fin[0] + fin[1] + fin[2] + fin[3]) /
                         ((double)HALF * (double)HALF));
}

extern "C" void kernel_launch(void* const* d_in, const int* in_sizes, int n_in,
                              void* d_out, int out_size, void* d_ws, size_t ws_size,
                              hipStream_t stream) {
    const float* src = (const float*)d_in[0];
    const float* tgt = (const float*)d_in[1];
    float* out = (float*)d_out;

    double* wsd        = (double*)d_ws;
    int* ticks         = (int*)((char*)d_ws + WS_TICK_OFF);
    float* sq          = (float*)((char*)d_ws + WS_SQ_OFF);
    unsigned short* G2 = (unsigned short*)((char*)d_ws + WS_G_OFF);

    // zero colsum/negg/sqsum/slots/tickets every launch
    hipMemsetAsync(d_ws, 0, WS_SQ_OFF, stream);

    k_prep<<<NROW / 32, 256, 0, stream>>>(src, tgt, G2, sq, wsd, &ticks[0]);
    k_mmd<<<NBLK, 256, 0, stream>>>(G2, sq, wsd, &wsd[WS_D_SLOT], out, &ticks[1]);
}

// Round 8
// 195.354 us; speedup vs baseline: 1.0131x; 1.0131x over previous
//
#include <hip/hip_runtime.h>
#include <hip/hip_bf16.h>

// MMD loss: source/target 4096x256 fp32, output = scalar fp32. N=8192, D=256.
//
// Two kernels total (last-block tickets fuse the scalar stages):
//  k_prep : fp32 -> bf16 in MFMA-native tiled layout G2 + row sq[] (from the
//           SAME bf16 values -> diagonal exact) + colsum/sqsum atomics;
//           LAST block computes neg_gamma2 = -log2(e)/(16*bw).
//  k_mmd  : one wave per 64x64 pair-tile (upper triangle), fragments loaded
//           straight from L2 (G2 frag = contiguous 1KB block), HALF-K (128)
//           register-resident per step -> one vmcnt wait per half, 64-MFMA
//           burst under s_setprio. No LDS, no barriers in the hot path.
//           LAST block reduces the 256 slot accumulators and writes out.
//
// G2 layout: tile t (64 rows), frag(kc,fr) contiguous 1KB:
//   G2[t*16384 + (kc*4+fr)*512 + lane*8 + e]
//   row = t*64 + fr*16 + (lane&15); k = kc*32 + (lane>>4)*8 + e
// (A- and B-fragment layouts coincide for the Gram product.)
//
// ws doubles: d[0..255]=colsum, d[256]=neg_gamma2, d[257]=sqsum,
//             d[258..513]=slots; ints at byte 4112: tick_prep, tick_mmd;
//             float sq[8192] at 4608; bf16 G2[8192*256] at 40960.
#define WS_D_COLSUM 0
#define WS_D_NEGG   256
#define WS_D_SQSUM  257
#define WS_D_SLOT   258
#define WS_SLOTS    256
#define WS_TICK_OFF 4112
#define WS_SQ_OFF   4608
#define WS_G_OFF    40960

#define NROW 8192
#define HALF 4096
#define DIM  256
#define TT   64
#define NT   128                   // row-tiles
#define NPAIR (NT * (NT + 1) / 2)  // 8256
#define NBLK  (NPAIR / 4)          // 2064 blocks x 4 waves
#define TILE_US 16384              // ushorts per tile (32 KB)

typedef short  short8 __attribute__((ext_vector_type(8)));
typedef float  f32x4  __attribute__((ext_vector_type(4)));
typedef unsigned short us4 __attribute__((ext_vector_type(4)));

static __device__ __forceinline__ unsigned short f2bfbits(float f) {
    __hip_bfloat16 h = __float2bfloat16(f);   // RNE
    return *reinterpret_cast<unsigned short*>(&h);
}
static __device__ __forceinline__ float bfbits2f(unsigned short u) {
    return __uint_as_float(((unsigned int)u) << 16);
}

// ---------- kernel A: cvt->G2 + row-sq + colsum/sqsum + bandwidth ----------
// 256 blocks x 256 threads; block handles 32 rows; wave w rows r0+w+4i, i<8.
__global__ __launch_bounds__(256) void k_prep(const float* __restrict__ src,
                                              const float* __restrict__ tgt,
                                              unsigned short* __restrict__ G2,
                                              float* __restrict__ sq,
                                              double* __restrict__ wsd,
                                              int* __restrict__ tick) {
    __shared__ float cs_lds[4 * 256];
    __shared__ double sq_lds[4];
    __shared__ double red2[256];
    __shared__ int is_last;

    int t = threadIdx.x, wid = t >> 6, lane = t & 63;
    int r0 = blockIdx.x * 32;
    int c4 = lane * 4;
    // G2 lane-invariant part: kc=lane>>3, kl=(lane>>1)&3, e4=(lane&1)*4
    int lanepart = (lane >> 3) * 2048 + ((lane >> 1) & 3) * 128 + (lane & 1) * 4;

    float cs0 = 0.f, cs1 = 0.f, cs2 = 0.f, cs3 = 0.f;
    double wsq = 0.0;
    for (int i = 0; i < 8; ++i) {
        int row = r0 + wid + i * 4;
        const float* base = (row < HALF) ? (src + (size_t)row * DIM)
                                         : (tgt + (size_t)(row - HALF) * DIM);
        float4 v = *(const float4*)(base + c4);
        unsigned short u0 = f2bfbits(v.x), u1 = f2bfbits(v.y),
                       u2 = f2bfbits(v.z), u3 = f2bfbits(v.w);
        us4 uu = {u0, u1, u2, u3};
        size_t tb = (size_t)(row >> 6) * TILE_US + (((row >> 4) & 3) * 512) + ((row & 15) * 8);
        *(us4*)(G2 + tb + lanepart) = uu;
        float r0f = bfbits2f(u0), r1f = bfbits2f(u1),
              r2f = bfbits2f(u2), r3f = bfbits2f(u3);
        cs0 += r0f; cs1 += r1f; cs2 += r2f; cs3 += r3f;
        float s = r0f * r0f + r1f * r1f + r2f * r2f + r3f * r3f;
        #pragma unroll
        for (int off = 32; off; off >>= 1) s += __shfl_down(s, off);
        if (lane == 0) { sq[row] = s; wsq += (double)s; }
    }
    cs_lds[wid * 256 + c4 + 0] = cs0;
    cs_lds[wid * 256 + c4 + 1] = cs1;
    cs_lds[wid * 256 + c4 + 2] = cs2;
    cs_lds[wid * 256 + c4 + 3] = cs3;
    if (lane == 0) sq_lds[wid] = wsq;
    __syncthreads();
    double s = (double)cs_lds[t] + (double)cs_lds[256 + t] +
               (double)cs_lds[512 + t] + (double)cs_lds[768 + t];
    atomicAdd(&wsd[WS_D_COLSUM + t], s);
    if (t == 0)
        atomicAdd(&wsd[WS_D_SQSUM], sq_lds[0] + sq_lds[1] + sq_lds[2] + sq_lds[3]);

    // ---- last block computes bandwidth ----
    __threadfence();
    if (t == 0) is_last = (atomicAdd(tick, 1) == (int)gridDim.x - 1);
    __syncthreads();
    if (!is_last) return;
    double c = atomicAdd(&wsd[WS_D_COLSUM + t], 0.0);  // coherent read-back
    red2[t] = c * c;
    __syncthreads();
    for (int off = 128; off; off >>= 1) {
        if (t < off) red2[t] += red2[t + off];
        __syncthreads();
    }
    if (t == 0) {
        double S = atomicAdd(&wsd[WS_D_SQSUM], 0.0);
        const double N = (double)NROW;
        double sum_l2 = 2.0 * N * S - 2.0 * red2[0];
        double bw = sum_l2 / (N * N - N);
        bw = bw / 4.0;  // KERNEL_MUL ** (KERNEL_NUM//2) = 2^2
        wsd[WS_D_NEGG] = -1.4426950408889634 / (16.0 * bw);  // exp2 scaling
    }
}

// ---------- kernel D: one wave per 64x64 pair-tile, register-resident K ----
__global__ __launch_bounds__(256, 2) void k_mmd(const unsigned short* __restrict__ G2,
                                                const float* __restrict__ sq,
                                                const double* __restrict__ wsd,
                                                double* __restrict__ slots,
                                                float* __restrict__ out,
                                                int* __restrict__ tick) {
    __shared__ int is_last;
    __shared__ double fin[4];

    // XCD-chunked bijective swizzle (NBLK = 2064 = 8*258)
    int bid = blockIdx.x;
    int swz = (bid & 7) * (NBLK / 8) + (bid >> 3);

    int t = threadIdx.x, wid = t >> 6, lane = t & 63;
    int p = swz * 4 + wid;   // pair index 0..8255 (wave-uniform)

    // closed-form triangular decode: start(ti) = 128*ti - ti*(ti-1)/2
    int ti = (int)((257.0f - sqrtf(66049.0f - 8.0f * (float)p)) * 0.5f);
    ti = ti < 0 ? 0 : (ti > 127 ? 127 : ti);
    while (ti > 0 && p < 128 * ti - ((ti * (ti - 1)) >> 1)) --ti;
    while (p >= 128 * (ti + 1) - (((ti + 1) * ti) >> 1)) ++ti;
    int tj = ti + (p - (128 * ti - ((ti * (ti - 1)) >> 1)));

    const unsigned short* Ab = G2 + (size_t)ti * TILE_US;
    const unsigned short* Bb = G2 + (size_t)tj * TILE_US;
    int lo = lane * 8;

    const f32x4 zero4 = {0.f, 0.f, 0.f, 0.f};
    f32x4 acc[4][4];
    #pragma unroll
    for (int i = 0; i < 4; ++i)
        #pragma unroll
        for (int j = 0; j < 4; ++j) acc[i][j] = zero4;

    #pragma unroll
    for (int h = 0; h < 2; ++h) {
        short8 a[4][4], b[4][4];   // [kf][fr] — all compile-time indexed
        #pragma unroll
        for (int kf = 0; kf < 4; ++kf)
            #pragma unroll
            for (int fr = 0; fr < 4; ++fr) {
                int fo = (((h * 4 + kf) * 4 + fr) * 512) + lo;
                a[kf][fr] = *(const short8*)&Ab[fo];
                b[kf][fr] = *(const short8*)&Bb[fo];
            }
        __builtin_amdgcn_s_setprio(1);
        #pragma unroll
        for (int kf = 0; kf < 4; ++kf)
            #pragma unroll
            for (int i = 0; i < 4; ++i)
                #pragma unroll
                for (int j = 0; j < 4; ++j)
                    acc[i][j] = __builtin_amdgcn_mfma_f32_16x16x32_bf16(
                        a[kf][i], b[kf][j], acc[i][j], 0, 0, 0);
        __builtin_amdgcn_s_setprio(0);
    }

    // epilogue: x = l2*ng2 = min(sqa' + sqb' + acc*m2g, 0);  kernels = sum e^(2^i)
    // C/D layout (m89): col = lane&15, row = (lane>>4)*4 + reg
    int gi0 = ti * TT, gj0 = tj * TT;
    float ng2 = (float)wsd[WS_D_NEGG];       // negative
    float m2g = -2.0f * ng2;                 // positive
    int rl16 = lane & 15, rgrp = lane >> 4;

    float sqb4[4];
    #pragma unroll
    for (int j = 0; j < 4; ++j) sqb4[j] = sq[gj0 + j * 16 + rl16] * ng2;

    float tsum = 0.f;
    #pragma unroll
    for (int i = 0; i < 4; ++i) {
        float sqa4[4];
        #pragma unroll
        for (int rr = 0; rr < 4; ++rr)
            sqa4[rr] = sq[gi0 + i * 16 + rgrp * 4 + rr] * ng2;
        #pragma unroll
        for (int j = 0; j < 4; ++j) {
            #pragma unroll
            for (int rr = 0; rr < 4; ++rr) {
                float x = fminf(fmaf(acc[i][j][rr], m2g, sqa4[rr] + sqb4[j]), 0.f);
                float e   = exp2f(x);
                float e2  = e * e;
                float e4  = e2 * e2;
                float e8  = e4 * e4;
                float e16 = e8 * e8;
                tsum += (e + e2) + (e4 + e8) + e16;
            }
        }
    }

    float w = ((ti < NT / 2) == (tj < NT / 2)) ? 1.f : -1.f;
    if (ti != tj) w *= 2.f;   // off-diagonal tiles count twice (symmetry)
    double dsum = (double)tsum * (double)w;

    #pragma unroll
    for (int off = 32; off; off >>= 1) dsum += __shfl_down(dsum, off);
    if (lane == 0) atomicAdd(&slots[p & (WS_SLOTS - 1)], dsum);

    // ---- last block finalizes ----
    __syncthreads();
    __threadfence();
    if (t == 0) is_last = (atomicAdd(tick, 1) == (int)gridDim.x - 1);
    __syncthreads();
    if (!is_last) return;
    double v = atomicAdd(&slots[t], 0.0);  // coherent read-back
    #pragma unroll
    for (int off = 32; off; off >>= 1) v += __shfl_down(v, off);
    if (lane == 0) fin[wid] = v;
    __syncthreads();
    if (t == 0)
        out[0] = (float)((fin[0] + fin[1] + fin[2] + fin[3]) /
                         ((double)HALF * (double)HALF));
}

extern "C" void kernel_launch(void* const* d_in, const int* in_sizes, int n_in,
                              void* d_out, int out_size, void* d_ws, size_t ws_size,
                              hipStream_t stream) {
    const float* src = (const float*)d_in[0];
    const float* tgt = (const float*)d_in[1];
    float* out = (float*)d_out;

    double* wsd        = (double*)d_ws;
    int* ticks         = (int*)((char*)d_ws + WS_TICK_OFF);
    float* sq          = (float*)((char*)d_ws + WS_SQ_OFF);
    unsigned short* G2 = (unsigned short*)((char*)d_ws + WS_G_OFF);

    // zero colsum/negg/sqsum/slots/tickets every launch
    hipMemsetAsync(d_ws, 0, WS_SQ_OFF, stream);

    k_prep<<<NROW / 32, 256, 0, stream>>>(src, tgt, G2, sq, wsd, &ticks[0]);
    k_mmd<<<NBLK, 256, 0, stream>>>(G2, sq, wsd, &wsd[WS_D_SLOT], out, &ticks[1]);
}

// Round 9
// 180.906 us; speedup vs baseline: 1.0940x; 1.0799x over previous
//
#include <hip/hip_runtime.h>
#include <hip/hip_bf16.h>

// MMD loss: source/target 4096x256 fp32, output scalar fp32. N=8192, D=256.
// 2 kernels + 1 memset:
//  k_prep : fp32 -> bf16 G (row-major, LINEAR coalesced writes) + row sq[]
//           (from the SAME bf16 values -> diagonal exact) + colsum/sqsum
//           atomics; LAST block (ticket) computes neg_gamma2.
//  k_mmd  : R4-proven LDS-staged MFMA Gram pass over upper-tri 128x128 tiles,
//           KC=32 double-buffered global_load_lds staging (one vmcnt(0)+
//           s_barrier per chunk), XOR-swizzled LDS; packed-f32 (v_pk) exp2
//           epilogue; LAST block reduces 64 slot accumulators -> out.
//
// ws doubles: d[0..255]=colsum, d[256]=neg_gamma2, d[257]=sqsum,
//             d[258..321]=slots(64); ints at 4112: tick_prep, tick_mmd;
//             float sq[8192] at 4608; bf16 G[8192*256] at 40960.
#define WS_D_COLSUM 0
#define WS_D_NEGG   256
#define WS_D_SQSUM  257
#define WS_D_SLOT   258
#define WS_SLOTS    64
#define WS_TICK_OFF 4112
#define WS_SQ_OFF   4608
#define WS_G_OFF    40960

#define NROW 8192
#define HALF 4096
#define DIM  256
#define TILE 128
#define NB   64                     // 8192/128 row-tiles
#define NBLK (NB * (NB + 1) / 2)    // 2080 upper-tri tile pairs
#define KC   32                     // k-chunk (64 B/row)
#define NC   (DIM / KC)             // 8 chunks
#define BUFE (TILE * KC)            // 4096 ushorts / buffer (8 KB)

typedef short  short8 __attribute__((ext_vector_type(8)));
typedef float  f32x4  __attribute__((ext_vector_type(4)));
typedef float  f32x2  __attribute__((ext_vector_type(2)));
typedef unsigned short us4 __attribute__((ext_vector_type(4)));

static __device__ __forceinline__ unsigned short f2bfbits(float f) {
    __hip_bfloat16 h = __float2bfloat16(f);   // RNE
    return *reinterpret_cast<unsigned short*>(&h);
}
static __device__ __forceinline__ float bfbits2f(unsigned short u) {
    return __uint_as_float(((unsigned int)u) << 16);
}
static __device__ __forceinline__ void gl_lds16(const void* g, void* l) {
    __builtin_amdgcn_global_load_lds(
        (const __attribute__((address_space(1))) void*)g,
        (__attribute__((address_space(3))) void*)l, 16, 0, 0);
}

// ---------- kernel A: cvt + row-sq + colsum/sqsum; last block: bandwidth ----
// 128 blocks x 256 threads; block handles 64 rows; wave w rows r0+w+4i, i<16.
__global__ __launch_bounds__(256) void k_prep(const float* __restrict__ src,
                                              const float* __restrict__ tgt,
                                              unsigned short* __restrict__ G,
                                              float* __restrict__ sq,
                                              double* __restrict__ wsd,
                                              int* __restrict__ tick) {
    __shared__ float cs_lds[4 * 256];
    __shared__ double sq_lds[4];
    __shared__ double red2[256];
    __shared__ int is_last;

    int t = threadIdx.x, wid = t >> 6, lane = t & 63;
    int r0 = blockIdx.x * 64;
    int c4 = lane * 4;

    float cs0 = 0.f, cs1 = 0.f, cs2 = 0.f, cs3 = 0.f;
    double wsq = 0.0;
    for (int i = 0; i < 16; ++i) {
        int row = r0 + wid + i * 4;
        const float* base = (row < HALF) ? (src + (size_t)row * DIM)
                                         : (tgt + (size_t)(row - HALF) * DIM);
        float4 v = *(const float4*)(base + c4);
        unsigned short u0 = f2bfbits(v.x), u1 = f2bfbits(v.y),
                       u2 = f2bfbits(v.z), u3 = f2bfbits(v.w);
        us4 uu = {u0, u1, u2, u3};
        *(us4*)(G + (size_t)row * DIM + c4) = uu;   // linear, coalesced
        float r0f = bfbits2f(u0), r1f = bfbits2f(u1),
              r2f = bfbits2f(u2), r3f = bfbits2f(u3);
        cs0 += r0f; cs1 += r1f; cs2 += r2f; cs3 += r3f;
        float s = r0f * r0f + r1f * r1f + r2f * r2f + r3f * r3f;
        #pragma unroll
        for (int off = 32; off; off >>= 1) s += __shfl_down(s, off);
        if (lane == 0) { sq[row] = s; wsq += (double)s; }
    }
    cs_lds[wid * 256 + c4 + 0] = cs0;
    cs_lds[wid * 256 + c4 + 1] = cs1;
    cs_lds[wid * 256 + c4 + 2] = cs2;
    cs_lds[wid * 256 + c4 + 3] = cs3;
    if (lane == 0) sq_lds[wid] = wsq;
    __syncthreads();
    double s = (double)cs_lds[t] + (double)cs_lds[256 + t] +
               (double)cs_lds[512 + t] + (double)cs_lds[768 + t];
    atomicAdd(&wsd[WS_D_COLSUM + t], s);
    if (t == 0)
        atomicAdd(&wsd[WS_D_SQSUM], sq_lds[0] + sq_lds[1] + sq_lds[2] + sq_lds[3]);
    __threadfence();
    __syncthreads();
    if (t == 0) is_last = (atomicAdd(tick, 1) == (int)gridDim.x - 1);
    __syncthreads();
    if (!is_last) return;

    double c = atomicAdd(&wsd[WS_D_COLSUM + t], 0.0);  // coherent read-back
    red2[t] = c * c;
    __syncthreads();
    for (int off = 128; off; off >>= 1) {
        if (t < off) red2[t] += red2[t + off];
        __syncthreads();
    }
    if (t == 0) {
        double S = atomicAdd(&wsd[WS_D_SQSUM], 0.0);
        const double N = (double)NROW;
        double sum_l2 = 2.0 * N * S - 2.0 * red2[0];
        double bw = sum_l2 / (N * N - N);
        bw = bw / 4.0;  // KERNEL_MUL ** (KERNEL_NUM//2) = 2^2
        wsd[WS_D_NEGG] = -1.4426950408889634 / (16.0 * bw);  // exp2 scaling
    }
}

// ---------- kernel D: MFMA pairwise pass, double-buffered; last block: out --
// LDS [row][k] bf16, KC=32 (4 slots of 16 B). Physical slot p at row r holds
// logical slot p ^ ((r>>1)&3): 2-way-max bank aliasing on b128 frag reads,
// linear global_load_lds dest (source pre-swizzled, involution).
__global__ __launch_bounds__(256, 3) void k_mmd(const unsigned short* __restrict__ G,
                                                const float* __restrict__ sq,
                                                const double* __restrict__ wsd,
                                                double* __restrict__ slots,
                                                float* __restrict__ out,
                                                int* __restrict__ tick) {
    __shared__ unsigned short As[2 * BUFE];   // 16 KB
    __shared__ unsigned short Bs[2 * BUFE];   // 16 KB
    __shared__ double wsum[4];
    __shared__ int is_last;

    // decode linear block id -> (bi, bj) with bi <= bj
    int bi = 0, rem = blockIdx.x;
    while (rem >= NB - bi) { rem -= NB - bi; ++bi; }
    int bj = bi + rem;

    int t = threadIdx.x, wid = t >> 6, lane = t & 63;
    int wr = wid >> 1, wc = wid & 1;
    int rl = lane & 15, klane = lane >> 4;

    const unsigned short* Abase = G + (size_t)bi * TILE * DIM;
    const unsigned short* Bbase = G + (size_t)bj * TILE * DIM;

    // staging: wave stages rows [wid*32, wid*32+32); load i covers 16 rows
    // (lane -> row +(lane>>2), physical slot lane&3)
    int lr0 = wid * 32 + (lane >> 2);
    int slog0 = (lane & 3) ^ ((lr0 >> 1) & 3);
    int lr1 = lr0 + 16;
    int slog1 = (lane & 3) ^ ((lr1 >> 1) & 3);
    size_t ga0 = (size_t)lr0 * DIM + slog0 * 8;
    size_t ga1 = (size_t)lr1 * DIM + slog1 * 8;
    int ld0 = (wid * 32) * KC;
    int ld1 = (wid * 32 + 16) * KC;

    // fragment-read offsets (loop-invariant)
    int aoff[4], boff[4];
    #pragma unroll
    for (int f = 0; f < 4; ++f) {
        int ra = wr * 64 + f * 16 + rl;
        aoff[f] = ra * KC + ((klane ^ ((ra >> 1) & 3)) * 8);
        int rb = wc * 64 + f * 16 + rl;
        boff[f] = rb * KC + ((klane ^ ((rb >> 1) & 3)) * 8);
    }

    const f32x4 zero4 = {0.f, 0.f, 0.f, 0.f};
    f32x4 acc[4][4];
    #pragma unroll
    for (int i = 0; i < 4; ++i)
        #pragma unroll
        for (int j = 0; j < 4; ++j) acc[i][j] = zero4;

    #define STAGE(kc, b)                                                     \
        do {                                                                 \
            gl_lds16(Abase + ga0 + (kc) * KC, &As[(b) * BUFE + ld0]);        \
            gl_lds16(Bbase + ga0 + (kc) * KC, &Bs[(b) * BUFE + ld0]);        \
            gl_lds16(Abase + ga1 + (kc) * KC, &As[(b) * BUFE + ld1]);        \
            gl_lds16(Bbase + ga1 + (kc) * KC, &Bs[(b) * BUFE + ld1]);        \
        } while (0)

    STAGE(0, 0);
    #pragma unroll
    for (int kc = 0; kc < NC; ++kc) {
        asm volatile("s_waitcnt vmcnt(0)" ::: "memory");  // my 4 loads of kc done
        __builtin_amdgcn_s_barrier();                      // everyone's done
        __builtin_amdgcn_sched_barrier(0);
        if (kc + 1 < NC) STAGE(kc + 1, (kc + 1) & 1);      // safe: buf consumed at kc-1

        const unsigned short* Ab = &As[(kc & 1) * BUFE];
        const unsigned short* Bb = &Bs[(kc & 1) * BUFE];
        short8 af[4], bfv[4];
        #pragma unroll
        for (int f = 0; f < 4; ++f) {
            af[f]  = *(const short8*)&Ab[aoff[f]];
            bfv[f] = *(const short8*)&Bb[boff[f]];
        }
        #pragma unroll
        for (int i = 0; i < 4; ++i)
            #pragma unroll
            for (int j = 0; j < 4; ++j)
                acc[i][j] = __builtin_amdgcn_mfma_f32_16x16x32_bf16(
                    af[i], bfv[j], acc[i][j], 0, 0, 0);
    }
    #undef STAGE

    // ---- epilogue: packed-f32 exp2-squaring chain (no clamp: off-diag l2>0;
    // diag |x|<1e-7 -> error ~1e-9, see analysis) ----
    // C/D layout (m89): col = lane&15, row = (lane>>4)*4 + reg
    int gi0 = bi * TILE + wr * 64;
    int gj0 = bj * TILE + wc * 64;
    float ng2 = (float)wsd[WS_D_NEGG];        // negative
    float m2g = -2.0f * ng2;                  // positive
    f32x2 m2g2 = {m2g, m2g};
    int rgrp = lane >> 4;

    float sqb4[4];
    #pragma unroll
    for (int j = 0; j < 4; ++j) sqb4[j] = sq[gj0 + j * 16 + rl] * ng2;

    f32x2 tsv = {0.f, 0.f};
    #pragma unroll
    for (int i = 0; i < 4; ++i) {
        int base = gi0 + i * 16 + rgrp * 4;
        f32x2 sa01 = {sq[base + 0] * ng2, sq[base + 1] * ng2};
        f32x2 sa23 = {sq[base + 2] * ng2, sq[base + 3] * ng2};
        #pragma unroll
        for (int j = 0; j < 4; ++j) {
            f32x2 sb = {sqb4[j], sqb4[j]};
            f32x2 x01 = {acc[i][j][0], acc[i][j][1]};
            f32x2 x23 = {acc[i][j][2], acc[i][j][3]};
            x01 = x01 * m2g2 + (sa01 + sb);   // v_pk_fma + v_pk_add
            x23 = x23 * m2g2 + (sa23 + sb);
            f32x2 e01, e23;
            e01.x = exp2f(x01.x); e01.y = exp2f(x01.y);
            e23.x = exp2f(x23.x); e23.y = exp2f(x23.y);
            f32x2 p01 = e01 * e01, q01 = p01 * p01,
                  r01 = q01 * q01, s01 = r01 * r01;
            f32x2 p23 = e23 * e23, q23 = p23 * p23,
                  r23 = q23 * q23, s23 = r23 * r23;
            tsv += ((e01 + p01) + (q01 + r01)) + s01;
            tsv += ((e23 + p23) + (q23 + r23)) + s23;
        }
    }
    float tsum = tsv.x + tsv.y;

    float w = ((bi < 32) == (bj < 32)) ? 1.f : -1.f;
    if (bi != bj) w *= 2.f;   // off-diagonal tiles count twice (symmetry)
    double dsum = (double)tsum * (double)w;

    #pragma unroll
    for (int off = 32; off; off >>= 1) dsum += __shfl_down(dsum, off);
    if (lane == 0) wsum[wid] = dsum;
    __syncthreads();
    if (t == 0)
        atomicAdd(&slots[blockIdx.x & (WS_SLOTS - 1)],
                  wsum[0] + wsum[1] + wsum[2] + wsum[3]);
    __threadfence();
    __syncthreads();
    if (t == 0) is_last = (atomicAdd(tick, 1) == NBLK - 1);
    __syncthreads();
    if (!is_last) return;

    if (wid == 0) {
        double v = atomicAdd(&slots[lane], 0.0);  // coherent read-back
        #pragma unroll
        for (int off = 32; off; off >>= 1) v += __shfl_down(v, off);
        if (lane == 0)
            out[0] = (float)(v / ((double)HALF * (double)HALF));
    }
}

extern "C" void kernel_launch(void* const* d_in, const int* in_sizes, int n_in,
                              void* d_out, int out_size, void* d_ws, size_t ws_size,
                              hipStream_t stream) {
    const float* src = (const float*)d_in[0];
    const float* tgt = (const float*)d_in[1];
    float* out = (float*)d_out;

    double* wsd       = (double*)d_ws;
    int* ticks        = (int*)((char*)d_ws + WS_TICK_OFF);
    float* sq         = (float*)((char*)d_ws + WS_SQ_OFF);
    unsigned short* G = (unsigned short*)((char*)d_ws + WS_G_OFF);

    // zero colsum/negg/sqsum/slots/tickets every launch
    hipMemsetAsync(d_ws, 0, WS_SQ_OFF, stream);

    k_prep<<<NROW / 64, 256, 0, stream>>>(src, tgt, G, sq, wsd, &ticks[0]);
    k_mmd<<<NBLK, 256, 0, stream>>>(G, sq, wsd, &wsd[WS_D_SLOT], out, &ticks[1]);
}

// Round 10
// 65.455 us; speedup vs baseline: 3.0236x; 2.7638x over previous
//
#include <hip/hip_runtime.h>
#include <hip/hip_bf16.h>

// MMD loss: source/target 4096x256 fp32, output scalar fp32. N=8192, D=256.
// 4 kernels + 1 memset (NO device-scope fences / tickets — R8/R9 showed the
// per-block __threadfence() finalize costs ~110 us at 2080 blocks):
//  k_prep  : fp32 -> bf16 G (linear coalesced) + row sq[] (from the SAME
//            bf16 values -> diagonal exact) + 8-way banked colsum/sqsum.
//  k_bw    : reduce banked sums -> neg_gamma2 = -log2(e)/(16*bw).
//  k_mmd   : R4-proven MFMA Gram pass (triple-buffered global_load_lds,
//            counted vmcnt(4), XOR-swizzled LDS) + packed-f32 exp2 epilogue.
//  k_final : reduce 64 slots -> out.
//
// ws doubles: d[0..2047]=colsum8 (8 copies x 256), d[2048..2055]=sqsum8,
//             d[2056]=neg_gamma2, d[2057..2120]=slots(64);
//             float sq[8192] at byte 17152; bf16 G[8192*256] at byte 50176.
#define WS_D_COLSUM8 0
#define WS_D_SQSUM8  2048
#define WS_D_NEGG    2056
#define WS_D_SLOT    2057
#define WS_SLOTS     64
#define WS_MEMSET_B  16968
#define WS_SQ_OFF    17152
#define WS_G_OFF     50176

#define NROW 8192
#define HALF 4096
#define DIM  256
#define TILE 128
#define NB   64                     // 8192/128 row-tiles
#define NBLK (NB * (NB + 1) / 2)    // 2080 upper-tri tile pairs
#define KC   32                     // k-chunk (64 B/row)
#define NC   (DIM / KC)             // 8 chunks
#define BUFE (TILE * KC)            // 4096 ushorts / buffer (8 KB)

typedef short  short8 __attribute__((ext_vector_type(8)));
typedef float  f32x4  __attribute__((ext_vector_type(4)));
typedef float  f32x2  __attribute__((ext_vector_type(2)));
typedef unsigned short us4 __attribute__((ext_vector_type(4)));

static __device__ __forceinline__ unsigned short f2bfbits(float f) {
    __hip_bfloat16 h = __float2bfloat16(f);   // RNE
    return *reinterpret_cast<unsigned short*>(&h);
}
static __device__ __forceinline__ float bfbits2f(unsigned short u) {
    return __uint_as_float(((unsigned int)u) << 16);
}
static __device__ __forceinline__ void gl_lds16(const void* g, void* l) {
    __builtin_amdgcn_global_load_lds(
        (const __attribute__((address_space(1))) void*)g,
        (__attribute__((address_space(3))) void*)l, 16, 0, 0);
}

// ---------- kernel A: cvt + row-sq + banked colsum/sqsum ----------
// 512 blocks x 256 threads; block handles 16 rows; wave w rows r0+w+4i, i<4.
__global__ __launch_bounds__(256) void k_prep(const float* __restrict__ src,
                                              const float* __restrict__ tgt,
                                              unsigned short* __restrict__ G,
                                              float* __restrict__ sq,
                                              double* __restrict__ wsd) {
    __shared__ float cs_lds[4 * 256];
    __shared__ double sq_lds[4];

    int t = threadIdx.x, wid = t >> 6, lane = t & 63;
    int r0 = blockIdx.x * 16;
    int c4 = lane * 4;
    int bank = blockIdx.x & 7;

    float cs0 = 0.f, cs1 = 0.f, cs2 = 0.f, cs3 = 0.f;
    double wsq = 0.0;
    for (int i = 0; i < 4; ++i) {
        int row = r0 + wid + i * 4;
        const float* base = (row < HALF) ? (src + (size_t)row * DIM)
                                         : (tgt + (size_t)(row - HALF) * DIM);
        float4 v = *(const float4*)(base + c4);
        unsigned short u0 = f2bfbits(v.x), u1 = f2bfbits(v.y),
                       u2 = f2bfbits(v.z), u3 = f2bfbits(v.w);
        us4 uu = {u0, u1, u2, u3};
        *(us4*)(G + (size_t)row * DIM + c4) = uu;   // linear, coalesced
        float r0f = bfbits2f(u0), r1f = bfbits2f(u1),
              r2f = bfbits2f(u2), r3f = bfbits2f(u3);
        cs0 += r0f; cs1 += r1f; cs2 += r2f; cs3 += r3f;
        float s = r0f * r0f + r1f * r1f + r2f * r2f + r3f * r3f;
        #pragma unroll
        for (int off = 32; off; off >>= 1) s += __shfl_down(s, off);
        if (lane == 0) { sq[row] = s; wsq += (double)s; }
    }
    cs_lds[wid * 256 + c4 + 0] = cs0;
    cs_lds[wid * 256 + c4 + 1] = cs1;
    cs_lds[wid * 256 + c4 + 2] = cs2;
    cs_lds[wid * 256 + c4 + 3] = cs3;
    if (lane == 0) sq_lds[wid] = wsq;
    __syncthreads();
    double s = (double)cs_lds[t] + (double)cs_lds[256 + t] +
               (double)cs_lds[512 + t] + (double)cs_lds[768 + t];
    atomicAdd(&wsd[WS_D_COLSUM8 + bank * 256 + t], s);   // 64-deep contention
    if (t == 0)
        atomicAdd(&wsd[WS_D_SQSUM8 + bank],
                  sq_lds[0] + sq_lds[1] + sq_lds[2] + sq_lds[3]);
}

// ---------- kernel B: bandwidth -> neg_gamma2 = -log2(e)/(16*bw) ----------
__global__ __launch_bounds__(256) void k_bw(const float* __restrict__ sq,
                                            double* __restrict__ wsd) {
    __shared__ double red[256];
    __shared__ double red2[256];
    int t = threadIdx.x;
    double s = 0.0;
    for (int i = t; i < NROW; i += 256) s += (double)sq[i];
    double c = 0.0;
    #pragma unroll
    for (int p = 0; p < 8; ++p) c += wsd[WS_D_COLSUM8 + p * 256 + t];
    red[t]  = s;
    red2[t] = c * c;
    __syncthreads();
    for (int off = 128; off; off >>= 1) {
        if (t < off) { red[t] += red[t + off]; red2[t] += red2[t + off]; }
        __syncthreads();
    }
    if (t == 0) {
        const double N = (double)NROW;
        double sum_l2 = 2.0 * N * red[0] - 2.0 * red2[0];
        double bw = sum_l2 / (N * N - N);
        bw = bw / 4.0;  // KERNEL_MUL ** (KERNEL_NUM//2) = 2^2
        wsd[WS_D_NEGG] = -1.4426950408889634 / (16.0 * bw);  // exp2 scaling
    }
}

// ---------- kernel D: MFMA pairwise pass (R4-proven triple-buffer loop) ----
// LDS [row][k] bf16, KC=32 (4 slots of 16 B). Physical slot p at row r holds
// logical slot p ^ ((r>>1)&3): 2-way-max bank aliasing on b128 frag reads,
// linear global_load_lds dest (source pre-swizzled, involution).
__global__ __launch_bounds__(256, 3) void k_mmd(const unsigned short* __restrict__ G,
                                                const float* __restrict__ sq,
                                                const double* __restrict__ wsd,
                                                double* __restrict__ slots) {
    __shared__ unsigned short As[3 * BUFE];   // 24 KB
    __shared__ unsigned short Bs[3 * BUFE];   // 24 KB
    __shared__ double wsum[4];

    // decode linear block id -> (bi, bj) with bi <= bj
    int bi = 0, rem = blockIdx.x;
    while (rem >= NB - bi) { rem -= NB - bi; ++bi; }
    int bj = bi + rem;

    int t = threadIdx.x, wid = t >> 6, lane = t & 63;
    int wr = wid >> 1, wc = wid & 1;
    int rl = lane & 15, klane = lane >> 4;

    const unsigned short* Abase = G + (size_t)bi * TILE * DIM;
    const unsigned short* Bbase = G + (size_t)bj * TILE * DIM;

    // staging: wave stages rows [wid*32, wid*32+32); load i covers 16 rows
    // (lane -> row +(lane>>2), physical slot lane&3)
    int lr0 = wid * 32 + (lane >> 2);
    int slog0 = (lane & 3) ^ ((lr0 >> 1) & 3);
    int lr1 = lr0 + 16;
    int slog1 = (lane & 3) ^ ((lr1 >> 1) & 3);
    size_t ga0 = (size_t)lr0 * DIM + slog0 * 8;
    size_t ga1 = (size_t)lr1 * DIM + slog1 * 8;
    int ld0 = (wid * 32) * KC;
    int ld1 = (wid * 32 + 16) * KC;

    // fragment-read offsets (loop-invariant)
    int aoff[4], boff[4];
    #pragma unroll
    for (int f = 0; f < 4; ++f) {
        int ra = wr * 64 + f * 16 + rl;
        aoff[f] = ra * KC + ((klane ^ ((ra >> 1) & 3)) * 8);
        int rb = wc * 64 + f * 16 + rl;
        boff[f] = rb * KC + ((klane ^ ((rb >> 1) & 3)) * 8);
    }

    const f32x4 zero4 = {0.f, 0.f, 0.f, 0.f};
    f32x4 acc[4][4];
    #pragma unroll
    for (int i = 0; i < 4; ++i)
        #pragma unroll
        for (int j = 0; j < 4; ++j) acc[i][j] = zero4;

    #define STAGE(kc, b)                                                     \
        do {                                                                 \
            gl_lds16(Abase + ga0 + (kc) * KC, &As[(b) * BUFE + ld0]);        \
            gl_lds16(Bbase + ga0 + (kc) * KC, &Bs[(b) * BUFE + ld0]);        \
            gl_lds16(Abase + ga1 + (kc) * KC, &As[(b) * BUFE + ld1]);        \
            gl_lds16(Bbase + ga1 + (kc) * KC, &Bs[(b) * BUFE + ld1]);        \
        } while (0)

    // prologue: prefetch chunks 0 and 1
    STAGE(0, 0);
    STAGE(1, 1);

    #pragma unroll
    for (int kc = 0; kc < NC; ++kc) {
        // wait for chunk kc's 4 loads (oldest); keep chunk kc+1's in flight
        if (kc < NC - 1) { asm volatile("s_waitcnt vmcnt(4)" ::: "memory"); }
        else             { asm volatile("s_waitcnt vmcnt(0)" ::: "memory"); }
        __builtin_amdgcn_s_barrier();
        __builtin_amdgcn_sched_barrier(0);
        if (kc + 2 < NC) STAGE(kc + 2, (kc + 2) % 3);

        const unsigned short* Ab = &As[(kc % 3) * BUFE];
        const unsigned short* Bb = &Bs[(kc % 3) * BUFE];
        short8 af[4], bfv[4];
        #pragma unroll
        for (int f = 0; f < 4; ++f) {
            af[f]  = *(const short8*)&Ab[aoff[f]];
            bfv[f] = *(const short8*)&Bb[boff[f]];
        }
        #pragma unroll
        for (int i = 0; i < 4; ++i)
            #pragma unroll
            for (int j = 0; j < 4; ++j)
                acc[i][j] = __builtin_amdgcn_mfma_f32_16x16x32_bf16(
                    af[i], bfv[j], acc[i][j], 0, 0, 0);
    }
    #undef STAGE

    // ---- epilogue: packed-f32 exp2-squaring chain (no clamp: off-diag
    // l2 > 0; diag |x| < 1e-7 -> output error ~1e-9) ----
    // C/D layout (m89): col = lane&15, row = (lane>>4)*4 + reg
    int gi0 = bi * TILE + wr * 64;
    int gj0 = bj * TILE + wc * 64;
    float ng2 = (float)wsd[WS_D_NEGG];        // negative
    float m2g = -2.0f * ng2;                  // positive
    f32x2 m2g2 = {m2g, m2g};
    int rgrp = lane >> 4;

    float sqb4[4];
    #pragma unroll
    for (int j = 0; j < 4; ++j) sqb4[j] = sq[gj0 + j * 16 + rl] * ng2;

    f32x2 tsv = {0.f, 0.f};
    #pragma unroll
    for (int i = 0; i < 4; ++i) {
        int base = gi0 + i * 16 + rgrp * 4;
        f32x2 sa01 = {sq[base + 0] * ng2, sq[base + 1] * ng2};
        f32x2 sa23 = {sq[base + 2] * ng2, sq[base + 3] * ng2};
        #pragma unroll
        for (int j = 0; j < 4; ++j) {
            f32x2 sb = {sqb4[j], sqb4[j]};
            f32x2 x01 = {acc[i][j][0], acc[i][j][1]};
            f32x2 x23 = {acc[i][j][2], acc[i][j][3]};
            x01 = x01 * m2g2 + (sa01 + sb);   // v_pk_fma + v_pk_add
            x23 = x23 * m2g2 + (sa23 + sb);
            f32x2 e01, e23;
            e01.x = exp2f(x01.x); e01.y = exp2f(x01.y);
            e23.x = exp2f(x23.x); e23.y = exp2f(x23.y);
            f32x2 p01 = e01 * e01, q01 = p01 * p01,
                  r01 = q01 * q01, s01 = r01 * r01;
            f32x2 p23 = e23 * e23, q23 = p23 * p23,
                  r23 = q23 * q23, s23 = r23 * r23;
            tsv += ((e01 + p01) + (q01 + r01)) + s01;
            tsv += ((e23 + p23) + (q23 + r23)) + s23;
        }
    }
    float tsum = tsv.x + tsv.y;

    float w = ((bi < 32) == (bj < 32)) ? 1.f : -1.f;
    if (bi != bj) w *= 2.f;   // off-diagonal tiles count twice (symmetry)
    double dsum = (double)tsum * (double)w;

    #pragma unroll
    for (int off = 32; off; off >>= 1) dsum += __shfl_down(dsum, off);
    if (lane == 0) wsum[wid] = dsum;
    __syncthreads();
    if (t == 0)
        atomicAdd(&slots[blockIdx.x & (WS_SLOTS - 1)],
                  wsum[0] + wsum[1] + wsum[2] + wsum[3]);
}

// ---------- kernel E: finalize ----------
__global__ void k_final(const double* __restrict__ wsd, float* __restrict__ out) {
    double s = 0.0;
    for (int i = 0; i < WS_SLOTS; ++i) s += wsd[WS_D_SLOT + i];
    out[0] = (float)(s / ((double)HALF * (double)HALF));
}

extern "C" void kernel_launch(void* const* d_in, const int* in_sizes, int n_in,
                              void* d_out, int out_size, void* d_ws, size_t ws_size,
                              hipStream_t stream) {
    const float* src = (const float*)d_in[0];
    const float* tgt = (const float*)d_in[1];
    float* out = (float*)d_out;

    double* wsd       = (double*)d_ws;
    float* sq         = (float*)((char*)d_ws + WS_SQ_OFF);
    unsigned short* G = (unsigned short*)((char*)d_ws + WS_G_OFF);

    // zero colsum8/sqsum8/negg/slots every launch
    hipMemsetAsync(d_ws, 0, WS_MEMSET_B, stream);

    k_prep<<<NROW / 16, 256, 0, stream>>>(src, tgt, G, sq, wsd);
    k_bw<<<1, 256, 0, stream>>>(sq, wsd);
    k_mmd<<<NBLK, 256, 0, stream>>>(G, sq, wsd, &wsd[WS_D_SLOT]);
    k_final<<<1, 1, 0, stream>>>(wsd, out);
}

// Round 11
// 65.379 us; speedup vs baseline: 3.0271x; 1.0012x over previous
//
#include <hip/hip_runtime.h>
#include <hip/hip_bf16.h>

// MMD loss: source/target 4096x256 fp32, output scalar fp32. N=8192, D=256.
// 4 kernels, NO memset (R10 profile: hipMemsetAsync's fillBufferAligned cost
// 42 us/replay = 65% of wall time). Every ws location is written before read:
//  k_prep  : fp32 -> bf16 G (linear coalesced) + row sq[] (from the SAME
//            bf16 values -> diagonal exact) + per-block colsum/sqsum PARTIAL
//            STORES (no atomics -> no pre-zeroing needed).
//  k_bw    : reduce 128 partials -> neg_gamma2 = -log2(e)/(16*bw).
//  k_mmd   : R10-proven MFMA Gram pass (triple-buffered global_load_lds,
//            counted vmcnt(4), XOR-swizzled LDS, packed-f32 exp2 epilogue);
//            per-block result PLAIN STORE to slots[blockIdx.x].
//  k_final : reduce 2080 slots -> out.
//
// ws layout (bytes):
//   0      : double slots[2080]          -> 16640
//   16640  : double neg_gamma2           -> 16648
//   16648  : double sqpart[128]          -> 17672
//   17672  : float  cspart[128*256]      -> 148744
//   148744 : float  sq[8192]             -> 181512
//   181520 : bf16   G[8192*256] (16-B aligned) -> 4375824
#define WS_SLOT_OFF   0
#define WS_NEGG_OFF   16640
#define WS_SQPART_OFF 16648
#define WS_CSPART_OFF 17672
#define WS_SQ_OFF     148744
#define WS_G_OFF      181520

#define NROW 8192
#define HALF 4096
#define DIM  256
#define TILE 128
#define NB   64                     // 8192/128 row-tiles
#define NBLK (NB * (NB + 1) / 2)    // 2080 upper-tri tile pairs
#define KC   32                     // k-chunk (64 B/row)
#define NC   (DIM / KC)             // 8 chunks
#define BUFE (TILE * KC)            // 4096 ushorts / buffer (8 KB)
#define PREPB 128                   // k_prep blocks (64 rows each)

typedef short  short8 __attribute__((ext_vector_type(8)));
typedef float  f32x4  __attribute__((ext_vector_type(4)));
typedef float  f32x2  __attribute__((ext_vector_type(2)));
typedef unsigned short us4 __attribute__((ext_vector_type(4)));

static __device__ __forceinline__ unsigned short f2bfbits(float f) {
    __hip_bfloat16 h = __float2bfloat16(f);   // RNE
    return *reinterpret_cast<unsigned short*>(&h);
}
static __device__ __forceinline__ float bfbits2f(unsigned short u) {
    return __uint_as_float(((unsigned int)u) << 16);
}
static __device__ __forceinline__ void gl_lds16(const void* g, void* l) {
    __builtin_amdgcn_global_load_lds(
        (const __attribute__((address_space(1))) void*)g,
        (__attribute__((address_space(3))) void*)l, 16, 0, 0);
}

// ---------- kernel A: cvt + row-sq + per-block colsum/sqsum partials ----------
// 128 blocks x 256 threads; block handles 64 rows; wave w rows r0+w+4i, i<16.
__global__ __launch_bounds__(256) void k_prep(const float* __restrict__ src,
                                              const float* __restrict__ tgt,
                                              unsigned short* __restrict__ G,
                                              float* __restrict__ sq,
                                              float* __restrict__ cspart,
                                              double* __restrict__ sqpart) {
    __shared__ float cs_lds[4 * 256];
    __shared__ double sq_lds[4];

    int t = threadIdx.x, wid = t >> 6, lane = t & 63;
    int r0 = blockIdx.x * 64;
    int c4 = lane * 4;

    float cs0 = 0.f, cs1 = 0.f, cs2 = 0.f, cs3 = 0.f;
    double wsq = 0.0;
    for (int i = 0; i < 16; ++i) {
        int row = r0 + wid + i * 4;
        const float* base = (row < HALF) ? (src + (size_t)row * DIM)
                                         : (tgt + (size_t)(row - HALF) * DIM);
        float4 v = *(const float4*)(base + c4);
        unsigned short u0 = f2bfbits(v.x), u1 = f2bfbits(v.y),
                       u2 = f2bfbits(v.z), u3 = f2bfbits(v.w);
        us4 uu = {u0, u1, u2, u3};
        *(us4*)(G + (size_t)row * DIM + c4) = uu;   // linear, coalesced
        float r0f = bfbits2f(u0), r1f = bfbits2f(u1),
              r2f = bfbits2f(u2), r3f = bfbits2f(u3);
        cs0 += r0f; cs1 += r1f; cs2 += r2f; cs3 += r3f;
        float s = r0f * r0f + r1f * r1f + r2f * r2f + r3f * r3f;
        #pragma unroll
        for (int off = 32; off; off >>= 1) s += __shfl_down(s, off);
        if (lane == 0) { sq[row] = s; wsq += (double)s; }
    }
    cs_lds[wid * 256 + c4 + 0] = cs0;
    cs_lds[wid * 256 + c4 + 1] = cs1;
    cs_lds[wid * 256 + c4 + 2] = cs2;
    cs_lds[wid * 256 + c4 + 3] = cs3;
    if (lane == 0) sq_lds[wid] = wsq;
    __syncthreads();
    // thread t owns column t: cross-wave sum -> plain partial store
    float s = cs_lds[t] + cs_lds[256 + t] + cs_lds[512 + t] + cs_lds[768 + t];
    cspart[blockIdx.x * 256 + t] = s;
    if (t == 0)
        sqpart[blockIdx.x] = sq_lds[0] + sq_lds[1] + sq_lds[2] + sq_lds[3];
}

// ---------- kernel B: bandwidth -> neg_gamma2 = -log2(e)/(16*bw) ----------
__global__ __launch_bounds__(256) void k_bw(const float* __restrict__ cspart,
                                            const double* __restrict__ sqpart,
                                            double* __restrict__ negg) {
    __shared__ double red[256];
    __shared__ double red2[256];
    int t = threadIdx.x;
    double c = 0.0;
    for (int b = 0; b < PREPB; ++b) c += (double)cspart[b * 256 + t];
    double s = (t < PREPB) ? sqpart[t] : 0.0;
    red[t]  = s;
    red2[t] = c * c;
    __syncthreads();
    for (int off = 128; off; off >>= 1) {
        if (t < off) { red[t] += red[t + off]; red2[t] += red2[t + off]; }
        __syncthreads();
    }
    if (t == 0) {
        const double N = (double)NROW;
        double sum_l2 = 2.0 * N * red[0] - 2.0 * red2[0];
        double bw = sum_l2 / (N * N - N);
        bw = bw / 4.0;  // KERNEL_MUL ** (KERNEL_NUM//2) = 2^2
        negg[0] = -1.4426950408889634 / (16.0 * bw);  // exp2 scaling
    }
}

// ---------- kernel D: MFMA pairwise pass (R10-proven triple-buffer loop) ----
// LDS [row][k] bf16, KC=32 (4 slots of 16 B). Physical slot p at row r holds
// logical slot p ^ ((r>>1)&3): 2-way-max bank aliasing on b128 frag reads,
// linear global_load_lds dest (source pre-swizzled, involution).
__global__ __launch_bounds__(256, 3) void k_mmd(const unsigned short* __restrict__ G,
                                                const float* __restrict__ sq,
                                                const double* __restrict__ negg,
                                                double* __restrict__ slots) {
    __shared__ unsigned short As[3 * BUFE];   // 24 KB
    __shared__ unsigned short Bs[3 * BUFE];   // 24 KB
    __shared__ double wsum[4];

    // decode linear block id -> (bi, bj) with bi <= bj
    int bi = 0, rem = blockIdx.x;
    while (rem >= NB - bi) { rem -= NB - bi; ++bi; }
    int bj = bi + rem;

    int t = threadIdx.x, wid = t >> 6, lane = t & 63;
    int wr = wid >> 1, wc = wid & 1;
    int rl = lane & 15, klane = lane >> 4;

    const unsigned short* Abase = G + (size_t)bi * TILE * DIM;
    const unsigned short* Bbase = G + (size_t)bj * TILE * DIM;

    // staging: wave stages rows [wid*32, wid*32+32); load i covers 16 rows
    // (lane -> row +(lane>>2), physical slot lane&3)
    int lr0 = wid * 32 + (lane >> 2);
    int slog0 = (lane & 3) ^ ((lr0 >> 1) & 3);
    int lr1 = lr0 + 16;
    int slog1 = (lane & 3) ^ ((lr1 >> 1) & 3);
    size_t ga0 = (size_t)lr0 * DIM + slog0 * 8;
    size_t ga1 = (size_t)lr1 * DIM + slog1 * 8;
    int ld0 = (wid * 32) * KC;
    int ld1 = (wid * 32 + 16) * KC;

    // fragment-read offsets (loop-invariant)
    int aoff[4], boff[4];
    #pragma unroll
    for (int f = 0; f < 4; ++f) {
        int ra = wr * 64 + f * 16 + rl;
        aoff[f] = ra * KC + ((klane ^ ((ra >> 1) & 3)) * 8);
        int rb = wc * 64 + f * 16 + rl;
        boff[f] = rb * KC + ((klane ^ ((rb >> 1) & 3)) * 8);
    }

    const f32x4 zero4 = {0.f, 0.f, 0.f, 0.f};
    f32x4 acc[4][4];
    #pragma unroll
    for (int i = 0; i < 4; ++i)
        #pragma unroll
        for (int j = 0; j < 4; ++j) acc[i][j] = zero4;

    #define STAGE(kc, b)                                                     \
        do {                                                                 \
            gl_lds16(Abase + ga0 + (kc) * KC, &As[(b) * BUFE + ld0]);        \
            gl_lds16(Bbase + ga0 + (kc) * KC, &Bs[(b) * BUFE + ld0]);        \
            gl_lds16(Abase + ga1 + (kc) * KC, &As[(b) * BUFE + ld1]);        \
            gl_lds16(Bbase + ga1 + (kc) * KC, &Bs[(b) * BUFE + ld1]);        \
        } while (0)

    // prologue: prefetch chunks 0 and 1
    STAGE(0, 0);
    STAGE(1, 1);

    #pragma unroll
    for (int kc = 0; kc < NC; ++kc) {
        // wait for chunk kc's 4 loads (oldest); keep chunk kc+1's in flight
        if (kc < NC - 1) { asm volatile("s_waitcnt vmcnt(4)" ::: "memory"); }
        else             { asm volatile("s_waitcnt vmcnt(0)" ::: "memory"); }
        __builtin_amdgcn_s_barrier();
        __builtin_amdgcn_sched_barrier(0);
        if (kc + 2 < NC) STAGE(kc + 2, (kc + 2) % 3);

        const unsigned short* Ab = &As[(kc % 3) * BUFE];
        const unsigned short* Bb = &Bs[(kc % 3) * BUFE];
        short8 af[4], bfv[4];
        #pragma unroll
        for (int f = 0; f < 4; ++f) {
            af[f]  = *(const short8*)&Ab[aoff[f]];
            bfv[f] = *(const short8*)&Bb[boff[f]];
        }
        #pragma unroll
        for (int i = 0; i < 4; ++i)
            #pragma unroll
            for (int j = 0; j < 4; ++j)
                acc[i][j] = __builtin_amdgcn_mfma_f32_16x16x32_bf16(
                    af[i], bfv[j], acc[i][j], 0, 0, 0);
    }
    #undef STAGE

    // ---- epilogue: packed-f32 exp2-squaring chain (no clamp: off-diag
    // l2 > 0; diag |x| < 1e-7 -> output error ~1e-9) ----
    // C/D layout (m89): col = lane&15, row = (lane>>4)*4 + reg
    int gi0 = bi * TILE + wr * 64;
    int gj0 = bj * TILE + wc * 64;
    float ng2 = (float)negg[0];               // negative
    float m2g = -2.0f * ng2;                  // positive
    f32x2 m2g2 = {m2g, m2g};
    int rgrp = lane >> 4;

    float sqb4[4];
    #pragma unroll
    for (int j = 0; j < 4; ++j) sqb4[j] = sq[gj0 + j * 16 + rl] * ng2;

    f32x2 tsv = {0.f, 0.f};
    #pragma unroll
    for (int i = 0; i < 4; ++i) {
        int base = gi0 + i * 16 + rgrp * 4;
        f32x2 sa01 = {sq[base + 0] * ng2, sq[base + 1] * ng2};
        f32x2 sa23 = {sq[base + 2] * ng2, sq[base + 3] * ng2};
        #pragma unroll
        for (int j = 0; j < 4; ++j) {
            f32x2 sb = {sqb4[j], sqb4[j]};
            f32x2 x01 = {acc[i][j][0], acc[i][j][1]};
            f32x2 x23 = {acc[i][j][2], acc[i][j][3]};
            x01 = x01 * m2g2 + (sa01 + sb);   // v_pk_fma + v_pk_add
            x23 = x23 * m2g2 + (sa23 + sb);
            f32x2 e01, e23;
            e01.x = exp2f(x01.x); e01.y = exp2f(x01.y);
            e23.x = exp2f(x23.x); e23.y = exp2f(x23.y);
            f32x2 p01 = e01 * e01, q01 = p01 * p01,
                  r01 = q01 * q01, s01 = r01 * r01;
            f32x2 p23 = e23 * e23, q23 = p23 * p23,
                  r23 = q23 * q23, s23 = r23 * r23;
            tsv += ((e01 + p01) + (q01 + r01)) + s01;
            tsv += ((e23 + p23) + (q23 + r23)) + s23;
        }
    }
    float tsum = tsv.x + tsv.y;

    float w = ((bi < 32) == (bj < 32)) ? 1.f : -1.f;
    if (bi != bj) w *= 2.f;   // off-diagonal tiles count twice (symmetry)
    double dsum = (double)tsum * (double)w;

    #pragma unroll
    for (int off = 32; off; off >>= 1) dsum += __shfl_down(dsum, off);
    if (lane == 0) wsum[wid] = dsum;
    __syncthreads();
    if (t == 0)
        slots[blockIdx.x] = wsum[0] + wsum[1] + wsum[2] + wsum[3];  // plain store
}

// ---------- kernel E: finalize (reduce 2080 slots) ----------
__global__ __launch_bounds__(256) void k_final(const double* __restrict__ slots,
                                               float* __restrict__ out) {
    __shared__ double red[256];
    int t = threadIdx.x;
    double s = 0.0;
    for (int i = t; i < NBLK; i += 256) s += slots[i];
    red[t] = s;
    __syncthreads();
    for (int off = 128; off; off >>= 1) {
        if (t < off) red[t] += red[t + off];
        __syncthreads();
    }
    if (t == 0)
        out[0] = (float)(red[0] / ((double)HALF * (double)HALF));
}

extern "C" void kernel_launch(void* const* d_in, const int* in_sizes, int n_in,
                              void* d_out, int out_size, void* d_ws, size_t ws_size,
                              hipStream_t stream) {
    const float* src = (const float*)d_in[0];
    const float* tgt = (const float*)d_in[1];
    float* out = (float*)d_out;

    double* slots     = (double*)((char*)d_ws + WS_SLOT_OFF);
    double* negg      = (double*)((char*)d_ws + WS_NEGG_OFF);
    double* sqpart    = (double*)((char*)d_ws + WS_SQPART_OFF);
    float*  cspart    = (float*)((char*)d_ws + WS_CSPART_OFF);
    float*  sq        = (float*)((char*)d_ws + WS_SQ_OFF);
    unsigned short* G = (unsigned short*)((char*)d_ws + WS_G_OFF);

    k_prep<<<PREPB, 256, 0, stream>>>(src, tgt, G, sq, cspart, sqpart);
    k_bw<<<1, 256, 0, stream>>>(cspart, sqpart, negg);
    k_mmd<<<NBLK, 256, 0, stream>>>(G, sq, negg, slots);
    k_final<<<1, 256, 0, stream>>>(slots, out);
}